// Round 18
// baseline (635.265 us; speedup 1.0000x reference)
//
#include <hip/hip_runtime.h>
#include <math.h>

#define Bn 16
#define Tn 16384
#define Fn 32
#define Cn 64
#define Ln 10
#define ST 76   // LDS tile row stride (elements): 152B -> conflict-free patterns

typedef _Float16 v8h  __attribute__((ext_vector_type(8)));
typedef _Float16 v4h  __attribute__((ext_vector_type(4)));
typedef float    v16f __attribute__((ext_vector_type(16)));
typedef float    v4f  __attribute__((ext_vector_type(4)));

// ---------------------------------------------------------------------------
// k_prep: pack weights fp32 -> fp16 in PER-LANE FRAGMENT ORDER so the layer
// kernels' A-operand loads are fully coalesced (16B/lane, 1KB/wave bursts).
// wfgP[l][chunk][lane][8]:  chunk = ((tap*4 + kc)*2 + fg)*2 + ch32
// rsP [l][chunk][lane][8]:  chunk = (kc*2 + rsi)*2 + ch32
// ---------------------------------------------------------------------------
__global__ __launch_bounds__(256) void k_prep(const float* __restrict__ fw,
                                              const float* __restrict__ gw,
                                              const float* __restrict__ rw,
                                              const float* __restrict__ sw,
                                              _Float16* __restrict__ wfgP,
                                              _Float16* __restrict__ rsP)
{
    int gid = blockIdx.x * 256 + threadIdx.x;
    if (gid < Ln * 24576) {
        int l      = gid / 24576;
        int rem    = gid % 24576;
        int chunk  = rem >> 9;
        int within = rem & 511;
        int lane   = within >> 3, j = within & 7;
        int ch32 = chunk & 1;
        int fg   = (chunk >> 1) & 1;
        int kc   = (chunk >> 2) & 3;
        int tap  = chunk >> 4;
        int co = ch32 * 32 + (lane & 31);
        int ci = kc * 16 + (lane >> 5) * 8 + j;
        const float* wsrc = fg ? gw : fw;
        wfgP[gid] = (_Float16)wsrc[((l * 64 + co) * 64 + ci) * 3 + tap];
    }
    int gid2 = gid - Ln * 24576;
    if (gid2 >= 0 && gid2 < Ln * 8192) {
        int l      = gid2 / 8192;
        int rem    = gid2 % 8192;
        int chunk  = rem >> 9;
        int within = rem & 511;
        int lane   = within >> 3, j = within & 7;
        int ch32 = chunk & 1;
        int rsi  = (chunk >> 1) & 1;
        int kc   = chunk >> 2;
        int co = ch32 * 32 + (lane & 31);
        int ci = kc * 16 + (lane >> 5) * 8 + j;
        const float* wsrc = rsi ? sw : rw;
        rsP[gid2] = (_Float16)wsrc[(l * 64 + co) * 64 + ci];
    }
}

// ---------------------------------------------------------------------------
// XCD-aware block swizzle: same t-slice -> same XCD in every kernel/layer.
// ---------------------------------------------------------------------------
__device__ __forceinline__ int xcd_swizzle(int bx, int nblk)
{
    return (bx & 7) * (nblk >> 3) + (bx >> 3);
}

// ---------------------------------------------------------------------------
// k_input: h[b][t][c] = fp16( sum_f w_in[c][f] * x[b][t][f] + b_in[c] )
// ---------------------------------------------------------------------------
__global__ __launch_bounds__(256) void k_input(const float* __restrict__ x,
                                               const float* __restrict__ w_in,
                                               const float* __restrict__ b_in,
                                               _Float16* __restrict__ h)
{
    __shared__ _Float16 HT[256 * 64];   // 32KB
    const int tid = threadIdx.x;
    const int blk = xcd_swizzle(blockIdx.x, Tn / 256);
    const int t0  = blk * 256;
    const int t   = t0 + tid;
    const int bb  = blockIdx.y;
    const float* xp = x + ((size_t)bb * Tn + t) * Fn;
    float xv[32];
    #pragma unroll
    for (int i = 0; i < 8; ++i) {
        v4f v = *(const v4f*)&xp[i * 4];
        xv[i*4+0] = v[0]; xv[i*4+1] = v[1]; xv[i*4+2] = v[2]; xv[i*4+3] = v[3];
    }
    #pragma unroll
    for (int c8 = 0; c8 < 8; ++c8) {
        v8h o;
        #pragma unroll
        for (int j = 0; j < 8; ++j) {
            int c = c8 * 8 + j;                 // loop-uniform -> s_loads
            float a = b_in[c];
            #pragma unroll
            for (int f = 0; f < 32; ++f) a = fmaf(w_in[c * 32 + f], xv[f], a);
            o[j] = (_Float16)a;
        }
        const int p = (c8 + tid) & 7;           // bank-rotate chunk slot
        *(v8h*)&HT[tid * 64 + p * 8] = o;
    }
    __syncthreads();
    _Float16* hp = h + ((size_t)bb * Tn + t0) * 64;
    #pragma unroll
    for (int it = 0; it < 8; ++it) {
        const int g  = it * 256 + tid;
        const int tl = g >> 3, c8 = g & 7;
        const int p  = (c8 + tl) & 7;
        *(v8h*)&hp[g * 8] = *(const v8h*)&HT[tl * 64 + p * 8];
    }
}

// ---------------------------------------------------------------------------
// k_layer2: one WaveNet layer, TWO independent 64-t tiles per block.
// R15 lesson: k_layer is serial-chain/latency-bound (k_pair halved bytes ->
// dur = doubled chain; R13 bytes-20% -> dur-8%; R14 loads-33% -> neutral).
// Fix: two independent phase-chains (tiles tA, tA+64) interleaved at source
// level in the same instruction stream -> 2x VMEM queue depth and VALU/MFMA
// overlap per wave between barriers, with NO extra serial chain.  Weight
// fragments (aF/aG/aR/aS) loaded ONCE, used by both tiles.
// LDS 4 x 9.7KB = 38.9KB; acc regs 4 x v16f = 64 -> VGPR ~110 <= 128 cap.
// Block 256 = 4 waves; per tile: 64co x 64t; wave quarter 32co x 32t.
// mfma_f32_32x32x16_f16: A[m=lane&31][k=(lane>>5)*8+j], B[k][n=lane&31],
// D: col(n)=lane&31, row(m)=(reg&3)+8*(reg>>2)+4*(lane>>5).
// ---------------------------------------------------------------------------
__global__ __launch_bounds__(256, 4) void k_layer2(
    const _Float16* __restrict__ hin, _Float16* __restrict__ hout,
    _Float16* __restrict__ skip,
    const _Float16* __restrict__ wfg, const _Float16* __restrict__ rs,
    const float* __restrict__ fb, const float* __restrict__ gb,
    const float* __restrict__ rb, const float* __restrict__ sb,
    const int dil, const float skip_scale, const int write_h)
{
    __shared__ _Float16 P0[64 * ST];    // tile A buffers
    __shared__ _Float16 P1[64 * ST];
    __shared__ _Float16 Q0[64 * ST];    // tile B buffers
    __shared__ _Float16 Q1[64 * ST];    // total 38912B

    const int tid  = threadIdx.x;
    const int lane = tid & 63;
    const int wv   = tid >> 6;
    const int ch32 = wv & 1;
    const int ch   = ch32 * 32;
    const int tw   = (wv >> 1) * 32;
    const int hl   = lane >> 5;
    const int ln31 = lane & 31;
    const int bb   = blockIdx.y;
    const int tA   = xcd_swizzle(blockIdx.x, Tn / 128) * 128;
    const int tB   = tA + 64;
    const size_t hbase = (size_t)bb * Tn * 64;

    v8h zero8;
    #pragma unroll
    for (int j = 0; j < 8; ++j) zero8[j] = (_Float16)0.f;

    const int s_tl = tid >> 3;              // 0..31
    const int s_c  = (tid & 7) * 8;

#define STAGE2(DA, DB, OFF) do {                                              \
    _Pragma("unroll")                                                         \
    for (int it = 0; it < 2; ++it) {                                          \
        int tl = s_tl + it * 32;                                              \
        int tgA = tA + tl - (OFF);                                            \
        v8h vA = zero8;                                                       \
        if (tgA >= 0) vA = *(const v8h*)&hin[hbase + (size_t)tgA * 64 + s_c]; \
        *(v8h*)&(DA)[tl * ST + s_c] = vA;                                     \
        int tgB = tB + tl - (OFF);                                            \
        v8h vB = zero8;                                                       \
        if (tgB >= 0) vB = *(const v8h*)&hin[hbase + (size_t)tgB * 64 + s_c]; \
        *(v8h*)&(DB)[tl * ST + s_c] = vB;                                     \
    } } while (0)

#define WOFF(TAP, KC, FG) (((((TAP) * 4 + (KC)) * 2 + (FG)) * 2 + ch32) * 512 + lane * 8)
#define RSOFF(KC, RSI)    ((((KC) * 2 + (RSI)) * 2 + ch32) * 512 + lane * 8)

// weights loaded once, applied to BOTH tiles' B-operands
#define MFMA_TAP2(SA, SB, TAP) do {                                           \
    _Pragma("unroll")                                                         \
    for (int kc = 0; kc < 4; ++kc) {                                          \
        const int kof = kc * 16 + hl * 8;                                     \
        v8h aF = *(const v8h*)&wfg[WOFF(TAP, kc, 0)];                         \
        v8h aG = *(const v8h*)&wfg[WOFF(TAP, kc, 1)];                         \
        v8h bA = *(const v8h*)&(SA)[(tw + ln31) * ST + kof];                  \
        v8h bB = *(const v8h*)&(SB)[(tw + ln31) * ST + kof];                  \
        accFA = __builtin_amdgcn_mfma_f32_32x32x16_f16(aF, bA, accFA, 0, 0, 0); \
        accGA = __builtin_amdgcn_mfma_f32_32x32x16_f16(aG, bA, accGA, 0, 0, 0); \
        accFB = __builtin_amdgcn_mfma_f32_32x32x16_f16(aF, bB, accFB, 0, 0, 0); \
        accGB = __builtin_amdgcn_mfma_f32_32x32x16_f16(aG, bB, accGB, 0, 0, 0); \
    } } while (0)

    // biases -> accumulator init (D row m maps to c = ch + 8q + 4hl + r)
    v16f accFA, accGA, accFB, accGB;
    #pragma unroll
    for (int q = 0; q < 4; ++q) {
        v4f fv = *(const v4f*)&fb[ch + 8 * q + 4 * hl];
        v4f gv = *(const v4f*)&gb[ch + 8 * q + 4 * hl];
        #pragma unroll
        for (int r = 0; r < 4; ++r) {
            accFA[q*4+r] = fv[r]; accGA[q*4+r] = gv[r];
            accFB[q*4+r] = fv[r]; accGB[q*4+r] = gv[r];
        }
    }

    STAGE2(P0, Q0, 2 * dil);
    __syncthreads();                        // S1: P0/Q0 ready
    STAGE2(P1, Q1, dil);                    // overlap tap1 loads with tap0 mfma
    MFMA_TAP2(P0, Q0, 0);
    __syncthreads();                        // S2: P1/Q1 ready, P0/Q0 reads done
    STAGE2(P0, Q0, 0);                      // overlap tap2 loads with tap1 mfma
    MFMA_TAP2(P1, Q1, 1);
    __syncthreads();                        // S3: P0/Q0 ready, P1/Q1 reads done
    MFMA_TAP2(P0, Q0, 2);                   // P0/Q0 hold hin[t] tiles - kept

    // act = tanh(f)*sigmoid(g) = (A-1)*rcp((A+1)*(1+B)) -> P1/Q1 scatter
    #pragma unroll
    for (int q = 0; q < 4; ++q) {
        v4h avA, avB;
        #pragma unroll
        for (int r = 0; r < 4; ++r) {
            {
                float f = accFA[q * 4 + r], g = accGA[q * 4 + r];
                float A = __expf(2.f * f), B = __expf(-g);
                float tAx = A + 1.f;
                float den = fmaf(tAx, B, tAx);
                avA[r] = (_Float16)((A - 1.f) * __builtin_amdgcn_rcpf(den));
            }
            {
                float f = accFB[q * 4 + r], g = accGB[q * 4 + r];
                float A = __expf(2.f * f), B = __expf(-g);
                float tAx = A + 1.f;
                float den = fmaf(tAx, B, tAx);
                avB[r] = (_Float16)((A - 1.f) * __builtin_amdgcn_rcpf(den));
            }
        }
        *(v4h*)&P1[(tw + ln31) * ST + ch + 8 * q + 4 * hl] = avA;
        *(v4h*)&Q1[(tw + ln31) * ST + ch + 8 * q + 4 * hl] = avB;
    }
    __syncthreads();                        // S4: act complete (cross c-half dep)

    // RS MFMA: weights once, both tiles
    v16f accRA, accSA, accRB, accSB;
    #pragma unroll
    for (int q = 0; q < 4; ++q) {
        v4f rv = *(const v4f*)&rb[ch + 8 * q + 4 * hl];
        v4f sv = *(const v4f*)&sb[ch + 8 * q + 4 * hl];
        #pragma unroll
        for (int r = 0; r < 4; ++r) {
            accRA[q*4+r] = rv[r]; accSA[q*4+r] = sv[r];
            accRB[q*4+r] = rv[r]; accSB[q*4+r] = sv[r];
        }
    }
    #pragma unroll
    for (int kc = 0; kc < 4; ++kc) {
        const int kof = kc * 16 + hl * 8;
        v8h aR = *(const v8h*)&rs[RSOFF(kc, 0)];
        v8h aS = *(const v8h*)&rs[RSOFF(kc, 1)];
        v8h bA = *(const v8h*)&P1[(tw + ln31) * ST + kof];
        v8h bB = *(const v8h*)&Q1[(tw + ln31) * ST + kof];
        accRA = __builtin_amdgcn_mfma_f32_32x32x16_f16(aR, bA, accRA, 0, 0, 0);
        accSA = __builtin_amdgcn_mfma_f32_32x32x16_f16(aS, bA, accSA, 0, 0, 0);
        accRB = __builtin_amdgcn_mfma_f32_32x32x16_f16(aR, bB, accRB, 0, 0, 0);
        accSB = __builtin_amdgcn_mfma_f32_32x32x16_f16(aS, bB, accSB, 0, 0, 0);
    }

    // R epilogue in-place on P0/Q0 (hold hin tiles): h_new = (h + R)*0.7071
    if (write_h) {
        #pragma unroll
        for (int q = 0; q < 4; ++q) {
            _Float16* cA = &P0[(tw + ln31) * ST + ch + 8 * q + 4 * hl];
            _Float16* cB = &Q0[(tw + ln31) * ST + ch + 8 * q + 4 * hl];
            v4h hA = *(const v4h*)cA, hB = *(const v4h*)cB;
            v4h nA, nB;
            #pragma unroll
            for (int r = 0; r < 4; ++r) {
                nA[r] = (_Float16)(((float)hA[r] + accRA[q * 4 + r]) * 0.7071f);
                nB[r] = (_Float16)(((float)hB[r] + accRB[q * 4 + r]) * 0.7071f);
            }
            *(v4h*)cA = nA;
            *(v4h*)cB = nB;
        }
    }
    __syncthreads();                        // S5: rs-reads done, P0/Q0 = hout tiles

    // S scatter -> P1/Q1 (act dead): skip contribution (bias already in accS)
    #pragma unroll
    for (int q = 0; q < 4; ++q) {
        v4h sA, sB;
        #pragma unroll
        for (int r = 0; r < 4; ++r) {
            sA[r] = (_Float16)accSA[q * 4 + r];
            sB[r] = (_Float16)accSB[q * 4 + r];
        }
        *(v4h*)&P1[(tw + ln31) * ST + ch + 8 * q + 4 * hl] = sA;
        *(v4h*)&Q1[(tw + ln31) * ST + ch + 8 * q + 4 * hl] = sB;
    }
    // hout coalesced stores (safe after S5)
    if (write_h) {
        #pragma unroll
        for (int it = 0; it < 2; ++it) {
            int tl = s_tl + it * 32;
            *(v8h*)&hout[hbase + (size_t)(tA + tl) * 64 + s_c] = *(const v8h*)&P0[tl * ST + s_c];
            *(v8h*)&hout[hbase + (size_t)(tB + tl) * 64 + s_c] = *(const v8h*)&Q0[tl * ST + s_c];
        }
    }
    __syncthreads();                        // S6: skip tiles complete

    // skip coalesced RMW from P1/Q1 (scale=0 absorbs 0xAA ws poison, layer 0)
    #pragma unroll
    for (int it = 0; it < 2; ++it) {
        int tl = s_tl + it * 32;
        const size_t baseA = hbase + (size_t)(tA + tl) * 64 + s_c;
        const size_t baseB = hbase + (size_t)(tB + tl) * 64 + s_c;
        v8h skA = *(const v8h*)&skip[baseA];
        v8h skB = *(const v8h*)&skip[baseB];
        v8h pA = *(const v8h*)&P1[tl * ST + s_c];
        v8h pB = *(const v8h*)&Q1[tl * ST + s_c];
        v8h nA, nB;
        #pragma unroll
        for (int r = 0; r < 8; ++r) {
            nA[r] = (_Float16)((float)skA[r] * skip_scale + (float)pA[r]);
            nB[r] = (_Float16)((float)skB[r] * skip_scale + (float)pB[r]);
        }
        *(v8h*)&skip[baseA] = nA;
        *(v8h*)&skip[baseB] = nB;
    }
#undef STAGE2
#undef MFMA_TAP2
#undef WOFF
#undef RSOFF
}

// ---------------------------------------------------------------------------
// k_out: out[b][t] = ow2 @ relu(ow1 @ relu(skip[b][t][:]) + ob1) + ob2
// ---------------------------------------------------------------------------
__global__ __launch_bounds__(256) void k_out(const _Float16* __restrict__ skip,
                                             const float* __restrict__ ow1,
                                             const float* __restrict__ ob1,
                                             const float* __restrict__ ow2,
                                             const float* __restrict__ ob2,
                                             float* __restrict__ out)
{
    const int blk = xcd_swizzle(blockIdx.x, Tn / 256);
    const int t  = blk * 256 + threadIdx.x;
    const int bb = blockIdx.y;
    const _Float16* sp = skip + ((size_t)bb * Tn + t) * 64;
    float y[64];
    #pragma unroll
    for (int i = 0; i < 8; ++i) {
        v8h v = *(const v8h*)&sp[i * 8];
        #pragma unroll
        for (int j = 0; j < 8; ++j) y[i * 8 + j] = fmaxf((float)v[j], 0.f);
    }
    float o = ob2[0];
    for (int co = 0; co < 64; ++co) {          // weights uniform -> s_loads
        float a0 = ob1[co], a1 = 0.f;
        #pragma unroll
        for (int ci = 0; ci < 64; ci += 2) {
            a0 = fmaf(ow1[co * 64 + ci],     y[ci],     a0);
            a1 = fmaf(ow1[co * 64 + ci + 1], y[ci + 1], a1);
        }
        o = fmaf(ow2[co], fmaxf(a0 + a1, 0.f), o);
    }
    out[(size_t)bb * Tn + t] = o;
}

// ---------------------------------------------------------------------------
extern "C" void kernel_launch(void* const* d_in, const int* in_sizes, int n_in,
                              void* d_out, int out_size, void* d_ws, size_t ws_size,
                              hipStream_t stream)
{
    const float* x    = (const float*)d_in[0];
    const float* w_in = (const float*)d_in[1];
    const float* b_in = (const float*)d_in[2];
    const float* fw   = (const float*)d_in[3];
    const float* fb   = (const float*)d_in[4];
    const float* gw   = (const float*)d_in[5];
    const float* gb   = (const float*)d_in[6];
    const float* rw   = (const float*)d_in[7];
    const float* rb   = (const float*)d_in[8];
    const float* sw   = (const float*)d_in[9];
    const float* sb   = (const float*)d_in[10];
    const float* ow1  = (const float*)d_in[11];
    const float* ob1  = (const float*)d_in[12];
    const float* ow2  = (const float*)d_in[13];
    const float* ob2  = (const float*)d_in[14];
    float* out = (float*)d_out;

    const size_t n = (size_t)Bn * Tn * 64;
    _Float16* hA    = (_Float16*)d_ws;
    _Float16* hB    = hA + n;
    _Float16* skip  = hB + n;
    _Float16* wfg16 = skip + n;
    _Float16* rs16  = wfg16 + (size_t)Ln * 24576;

    dim3 blk(256);
    k_prep<<<dim3((Ln * 24576 + Ln * 8192 + 255) / 256), blk, 0, stream>>>(
        fw, gw, rw, sw, wfg16, rs16);
    k_input<<<dim3(Tn / 256, Bn), blk, 0, stream>>>(x, w_in, b_in, hA);

    const _Float16* cur = hA;
    _Float16* nxt = hB;
    for (int l = 0; l < Ln; ++l) {
        const int d = 1 << l;                  // dilations 1..512
        k_layer2<<<dim3(Tn / 128, Bn), blk, 0, stream>>>(
            cur, nxt, skip,
            wfg16 + (size_t)l * 24576, rs16 + (size_t)l * 8192,
            fb + l * Cn, gb + l * Cn, rb + l * Cn, sb + l * Cn,
            d, (l == 0) ? 0.f : 1.f,           // scale=0 absorbs 0xAA ws poison
            (l == Ln - 1) ? 0 : 1);            // layer 9: hout dead
        const _Float16* tmp = nxt; nxt = (_Float16*)cur; cur = tmp;
    }

    k_out<<<dim3(Tn / 256, Bn), blk, 0, stream>>>(skip, ow1, ob1, ow2, ob2, out);
}